// Round 6
// baseline (663.680 us; speedup 1.0000x reference)
//
#include <hip/hip_runtime.h>
#include <math.h>

#define NN 50000
#define NE 800000
#define D 64

typedef __attribute__((ext_vector_type(8))) short short8;
typedef __attribute__((ext_vector_type(4))) float f32x4;

// Compiler-only memory fence: LDS data handoffs between lanes of one wave are
// per-lane NoAlias to LLVM, which may hoist ds_read above the ds_write that
// produces the data (cross-lane dependence is invisible to per-thread AA).
// HW DS pipe is in-order per wave, so pinning program order is sufficient.
__device__ __forceinline__ void lds_fence() { asm volatile("" ::: "memory"); }

__device__ __forceinline__ float silu_f(float x) { return x / (1.0f + __expf(-x)); }
__device__ __forceinline__ unsigned short f2bf(float f) {
  unsigned int u = __float_as_uint(f);
  u += 0x7fffu + ((u >> 16) & 1u);
  return (unsigned short)(u >> 16);
}
__device__ __forceinline__ unsigned int pack2(float a, float b) {
  return (unsigned int)f2bf(a) | ((unsigned int)f2bf(b) << 16);
}
__device__ __forceinline__ short8 pack_frag(f32x4 a, f32x4 b) {
  union { unsigned int u[4]; short8 s; } r;
  r.u[0] = pack2(a[0], a[1]);
  r.u[1] = pack2(a[2], a[3]);
  r.u[2] = pack2(b[0], b[1]);
  r.u[3] = pack2(b[2], b[3]);
  return r.s;
}

// ---------------------------------------------------------------------------
// prep: permute fp32 weights into bf16 MFMA fragments.
// frag(nt,ks): elem(L,j) = W[ks*32 + (L>>4)*8 + j][nt*16 + (L&15)]
// ---------------------------------------------------------------------------
__global__ void prep_all(const float* __restrict__ ng_w2,
                         const float* __restrict__ eg_w1,
                         const float* __restrict__ eg_w2,
                         const float* __restrict__ mg_w1,
                         const float* __restrict__ mg_w2,
                         const float* __restrict__ ng_w1,
                         const float* __restrict__ up_w,
                         unsigned short* __restrict__ out) {
  int t = blockIdx.x * 256 + threadIdx.x;
  if (t >= 104 * 64) return;
  int frag = t >> 6, L = t & 63;
  const float* W; int K, N, f0;
  if (frag < 8)       { W = ng_w2; K = 64;  N = 64;  f0 = 0; }
  else if (frag < 16) { W = eg_w1; K = 64;  N = 64;  f0 = 8; }
  else if (frag < 24) { W = eg_w2; K = 64;  N = 64;  f0 = 16; }
  else if (frag < 72) { W = mg_w1; K = 192; N = 128; f0 = 24; }
  else if (frag < 88) { W = mg_w2; K = 128; N = 64;  f0 = 72; }
  else if (frag < 96) { W = ng_w1; K = 64;  N = 64;  f0 = 88; }
  else                { W = up_w;  K = 64;  N = 64;  f0 = 96; }
  int lf = frag - f0;
  int kd = K >> 5;
  int nt = lf / kd, ks = lf % kd;
  int kb = ks * 32 + (L >> 4) * 8;
  int nc = nt * 16 + (L & 15);
  unsigned int p[4];
#pragma unroll
  for (int jj = 0; jj < 4; ++jj) {
    float a = W[(size_t)(kb + 2 * jj) * N + nc];
    float b = W[(size_t)(kb + 2 * jj + 1) * N + nc];
    p[jj] = pack2(a, b);
  }
  *(uint4*)(out + (size_t)frag * 512 + L * 8) = make_uint4(p[0], p[1], p[2], p[3]);
}

// ---------------------------------------------------------------------------
// node_pre: h_ng = s @ ng_w1[0:64] + b1, MFMA, 32 nodes/wave, barrier-free.
// ---------------------------------------------------------------------------
__global__ __launch_bounds__(256, 4) void node_pre(
    const float* __restrict__ s, const float* __restrict__ ng_b1,
    const unsigned short* __restrict__ WF, float* __restrict__ h_ng) {
  __shared__ __align__(16) char sm[4 * 8704];
  int tid = threadIdx.x, w = tid >> 6, lane = tid & 63;
  int l15 = lane & 15, q = lane >> 4, fb = q * 8;
  char* my = sm + w * 8704;
  int nb = (blockIdx.x * 4 + w) * 32;
  if (nb >= NN) return;

  short8 Bs[2][2];
#pragma unroll
  for (int h = 0; h < 2; ++h)
#pragma unroll
    for (int kt = 0; kt < 2; ++kt) {
      int n = nb + h * 16 + l15; if (n >= NN) n = NN - 1;
      f32x4 x0 = *(const f32x4*)(s + (size_t)n * D + kt * 32 + fb);
      f32x4 x1 = *(const f32x4*)(s + (size_t)n * D + kt * 32 + fb + 4);
      Bs[h][kt] = pack_frag(x0, x1);
    }
  short8 F[4][2]; f32x4 bb[4];
#pragma unroll
  for (int mt = 0; mt < 4; ++mt) {
    F[mt][0] = *(const short8*)(WF + (size_t)(88 + mt * 2 + 0) * 512 + lane * 8);
    F[mt][1] = *(const short8*)(WF + (size_t)(88 + mt * 2 + 1) * 512 + lane * 8);
    bb[mt] = *(const f32x4*)(ng_b1 + mt * 16 + 4 * q);
  }
#pragma unroll
  for (int h = 0; h < 2; ++h)
#pragma unroll
    for (int mt = 0; mt < 4; ++mt) {
      f32x4 acc = {0.f, 0.f, 0.f, 0.f};
      acc = __builtin_amdgcn_mfma_f32_16x16x32_bf16(F[mt][0], Bs[h][0], acc, 0, 0, 0);
      acc = __builtin_amdgcn_mfma_f32_16x16x32_bf16(F[mt][1], Bs[h][1], acc, 0, 0, 0);
      acc[0] += bb[mt][0]; acc[1] += bb[mt][1]; acc[2] += bb[mt][2]; acc[3] += bb[mt][3];
      *(f32x4*)(my + (((h * 16 + l15) * 68 + mt * 16 + 4 * q) << 2)) = acc;
    }
  lds_fence();
#pragma unroll
  for (int h = 0; h < 2; ++h)
#pragma unroll
    for (int e = 0; e < 16; ++e) {
      int n = nb + h * 16 + e;
      if (n < NN) {
        float val = *(const float*)(my + (((h * 16 + e) * 68 + lane) << 2));
        h_ng[(size_t)n * D + lane] = val;
      }
    }
}

// ---------------------------------------------------------------------------
// edge_mfma: full edge pipeline, 32 edges/wave, zero __syncthreads.
// Wave-private LDS: two ping-pong tile buffers (32 rows x 18 dw each) used
// as a 32-feature staging window for the MFMA C->B layout transform, and
// (reused) for the final 8-edge scatter transpose. 4.5 KB per wave.
// Every LDS write->read handoff is guarded by lds_fence() (see comment above).
// ---------------------------------------------------------------------------
#define TB 2304           // one tile buffer: 32 rows * 18 dw * 4 B
#define WSLICE (2 * TB)   // per-wave LDS

__device__ __forceinline__ void put_tile(char* buf, int l15, int q, int mtl,
                                         int h, unsigned int px, unsigned int py) {
  *(uint2*)(buf + (((h * 16 + l15) * 18 + mtl * 8 + 2 * q) << 2)) = make_uint2(px, py);
}
__device__ __forceinline__ short8 get_frag(const char* buf, int l15, int q, int h) {
  const char* p = buf + (((h * 16 + l15) * 18 + 4 * q) << 2);
  uint2 lo = *(const uint2*)p;
  uint2 hi = *(const uint2*)(p + 8);
  union { unsigned int u[4]; short8 s; } r;
  r.u[0] = lo.x; r.u[1] = lo.y; r.u[2] = hi.x; r.u[3] = hi.y;
  return r.s;
}

__global__ __launch_bounds__(256, 4) void edge_mfma(
    const float* __restrict__ v, const int* __restrict__ ei,
    const float* __restrict__ edge_attr, const float* __restrict__ evu,
    const float* __restrict__ ng_w1, const float* __restrict__ ng_b2,
    const float* __restrict__ eg_w1, const float* __restrict__ eg_b1,
    const float* __restrict__ eg_b2,
    const float* __restrict__ mg_b1, const float* __restrict__ mg_b2,
    const float* __restrict__ pe_w, const float* __restrict__ pe_b,
    const float* __restrict__ h_ng,
    const unsigned short* __restrict__ WF,
    float* __restrict__ s_agg, float* __restrict__ v_agg) {
  __shared__ __align__(16) char sm[4 * WSLICE];
  int tid = threadIdx.x, w = tid >> 6, lane = tid & 63;
  int l15 = lane & 15, q = lane >> 4, fb = q * 8;
  char* my = sm + w * WSLICE;
  int eb = (blockIdx.x * 4 + w) * 32;

  // ---- per-edge scalars (lane's edge = eb + h*16 + l15; replicated over q)
  int rown[2], coln[2];
  float rij[2], rji[2], uu0[2], uu1[2], uu2[2], cmag[2];
#pragma unroll
  for (int h = 0; h < 2; ++h) {
    int e = eb + h * 16 + l15;
    int r = ei[e], c = ei[NE + e];
    rown[h] = r; coln[h] = c;
    float u0 = evu[e * 3 + 0], u1 = evu[e * 3 + 1], u2 = evu[e * 3 + 2];
    uu0[h] = u0; uu1[h] = u1; uu2[h] = u2;
    float vi0 = v[r * 3 + 0], vi1 = v[r * 3 + 1], vi2 = v[r * 3 + 2];
    float vj0 = v[c * 3 + 0], vj1 = v[c * 3 + 1], vj2 = v[c * 3 + 2];
    rij[h] = 1.f - (vi0 * u0 + vi1 * u1 + vi2 * u2);
    rji[h] = 1.f + (vj0 * u0 + vj1 * u1 + vj2 * u2);
    float cx = vi1 * vj2 - vi2 * vj1;
    float cy = vi2 * vj0 - vi0 * vj2;
    float cz = vi0 * vj1 - vi1 * vj0;
    cmag[h] = sqrtf(cx * cx + cy * cy + cz * cz);
  }

  f32x4 w1l[2][2];
#pragma unroll
  for (int kt = 0; kt < 2; ++kt) {
    w1l[kt][0] = *(const f32x4*)(ng_w1 + 64 * 64 + kt * 32 + fb);
    w1l[kt][1] = *(const f32x4*)(ng_w1 + 64 * 64 + kt * 32 + fb + 4);
  }

  short8 Bin[2][6];  // B-frags feeding the message MLP: nfi(0,1) nfj(2,3) ef(4,5)

  // ======== node-feature branch: a_i, a_j -> nf_i, nf_j ========
  {
    short8 Bai[2][2], Baj[2][2];
#pragma unroll
    for (int h = 0; h < 2; ++h)
#pragma unroll
      for (int kt = 0; kt < 2; ++kt) {
        const float* pr = h_ng + (size_t)rown[h] * D + kt * 32 + fb;
        const float* pc = h_ng + (size_t)coln[h] * D + kt * 32 + fb;
        f32x4 a0 = *(const f32x4*)pr, a1 = *(const f32x4*)(pr + 4);
        f32x4 b0 = *(const f32x4*)pc, b1 = *(const f32x4*)(pc + 4);
        f32x4 si0, si1, sj0, sj1;
#pragma unroll
        for (int c2 = 0; c2 < 4; ++c2) {
          si0[c2] = silu_f(a0[c2] + rij[h] * w1l[kt][0][c2]);
          si1[c2] = silu_f(a1[c2] + rij[h] * w1l[kt][1][c2]);
          sj0[c2] = silu_f(b0[c2] + rji[h] * w1l[kt][0][c2]);
          sj1[c2] = silu_f(b1[c2] + rji[h] * w1l[kt][1][c2]);
        }
        Bai[h][kt] = pack_frag(si0, si1);
        Baj[h][kt] = pack_frag(sj0, sj1);
      }

    short8 F[4][2]; f32x4 bb[4];
#pragma unroll
    for (int mt = 0; mt < 4; ++mt) {
      F[mt][0] = *(const short8*)(WF + (size_t)(0 + mt * 2 + 0) * 512 + lane * 8);
      F[mt][1] = *(const short8*)(WF + (size_t)(0 + mt * 2 + 1) * 512 + lane * 8);
      bb[mt] = *(const f32x4*)(ng_b2 + mt * 16 + 4 * q);
    }
    // nf_i -> Bin[h][0..1]
#pragma unroll
    for (int kt = 0; kt < 2; ++kt) {
      char* buf = my + kt * TB;
#pragma unroll
      for (int mtl = 0; mtl < 2; ++mtl) {
        int mt = kt * 2 + mtl;
#pragma unroll
        for (int h = 0; h < 2; ++h) {
          f32x4 acc = {0.f, 0.f, 0.f, 0.f};
          acc = __builtin_amdgcn_mfma_f32_16x16x32_bf16(F[mt][0], Bai[h][0], acc, 0, 0, 0);
          acc = __builtin_amdgcn_mfma_f32_16x16x32_bf16(F[mt][1], Bai[h][1], acc, 0, 0, 0);
          put_tile(buf, l15, q, mtl, h,
                   pack2(acc[0] + bb[mt][0], acc[1] + bb[mt][1]),
                   pack2(acc[2] + bb[mt][2], acc[3] + bb[mt][3]));
        }
      }
      lds_fence();
#pragma unroll
      for (int h = 0; h < 2; ++h) Bin[h][kt] = get_frag(buf, l15, q, h);
      lds_fence();
    }
    // nf_j -> Bin[h][2..3]
#pragma unroll
    for (int kt = 0; kt < 2; ++kt) {
      char* buf = my + kt * TB;
#pragma unroll
      for (int mtl = 0; mtl < 2; ++mtl) {
        int mt = kt * 2 + mtl;
#pragma unroll
        for (int h = 0; h < 2; ++h) {
          f32x4 acc = {0.f, 0.f, 0.f, 0.f};
          acc = __builtin_amdgcn_mfma_f32_16x16x32_bf16(F[mt][0], Baj[h][0], acc, 0, 0, 0);
          acc = __builtin_amdgcn_mfma_f32_16x16x32_bf16(F[mt][1], Baj[h][1], acc, 0, 0, 0);
          put_tile(buf, l15, q, mtl, h,
                   pack2(acc[0] + bb[mt][0], acc[1] + bb[mt][1]),
                   pack2(acc[2] + bb[mt][2], acc[3] + bb[mt][3]));
        }
      }
      lds_fence();
#pragma unroll
      for (int h = 0; h < 2; ++h) Bin[h][2 + kt] = get_frag(buf, l15, q, h);
      lds_fence();
    }
  }

  // ======== edge-feature branch: Xe -> ae -> ef ========
  {
    short8 Bxe[2][2];
#pragma unroll
    for (int h = 0; h < 2; ++h)
#pragma unroll
      for (int kt = 0; kt < 2; ++kt) {
        const float* px = edge_attr + (size_t)(eb + h * 16 + l15) * D + kt * 32 + fb;
        f32x4 x0 = *(const f32x4*)px, x1 = *(const f32x4*)(px + 4);
        Bxe[h][kt] = pack_frag(x0, x1);
      }
    // ae = silu(Xe @ eg_w1 + b + cmag*w_last)
    short8 Bae[2][2];
    {
      short8 F[4][2]; f32x4 bb[4], el[4];
#pragma unroll
      for (int mt = 0; mt < 4; ++mt) {
        F[mt][0] = *(const short8*)(WF + (size_t)(8 + mt * 2 + 0) * 512 + lane * 8);
        F[mt][1] = *(const short8*)(WF + (size_t)(8 + mt * 2 + 1) * 512 + lane * 8);
        bb[mt] = *(const f32x4*)(eg_b1 + mt * 16 + 4 * q);
        el[mt] = *(const f32x4*)(eg_w1 + 64 * 64 + mt * 16 + 4 * q);
      }
#pragma unroll
      for (int kt = 0; kt < 2; ++kt) {
        char* buf = my + kt * TB;
#pragma unroll
        for (int mtl = 0; mtl < 2; ++mtl) {
          int mt = kt * 2 + mtl;
#pragma unroll
          for (int h = 0; h < 2; ++h) {
            f32x4 acc = {0.f, 0.f, 0.f, 0.f};
            acc = __builtin_amdgcn_mfma_f32_16x16x32_bf16(F[mt][0], Bxe[h][0], acc, 0, 0, 0);
            acc = __builtin_amdgcn_mfma_f32_16x16x32_bf16(F[mt][1], Bxe[h][1], acc, 0, 0, 0);
            float t0 = silu_f(acc[0] + bb[mt][0] + cmag[h] * el[mt][0]);
            float t1 = silu_f(acc[1] + bb[mt][1] + cmag[h] * el[mt][1]);
            float t2 = silu_f(acc[2] + bb[mt][2] + cmag[h] * el[mt][2]);
            float t3 = silu_f(acc[3] + bb[mt][3] + cmag[h] * el[mt][3]);
            put_tile(buf, l15, q, mtl, h, pack2(t0, t1), pack2(t2, t3));
          }
        }
        lds_fence();
#pragma unroll
        for (int h = 0; h < 2; ++h) Bae[h][kt] = get_frag(buf, l15, q, h);
        lds_fence();
      }
    }
    // ef = ae @ eg_w2 + b -> Bin[h][4..5]
    {
      short8 F[4][2]; f32x4 bb[4];
#pragma unroll
      for (int mt = 0; mt < 4; ++mt) {
        F[mt][0] = *(const short8*)(WF + (size_t)(16 + mt * 2 + 0) * 512 + lane * 8);
        F[mt][1] = *(const short8*)(WF + (size_t)(16 + mt * 2 + 1) * 512 + lane * 8);
        bb[mt] = *(const f32x4*)(eg_b2 + mt * 16 + 4 * q);
      }
#pragma unroll
      for (int kt = 0; kt < 2; ++kt) {
        char* buf = my + kt * TB;
#pragma unroll
        for (int mtl = 0; mtl < 2; ++mtl) {
          int mt = kt * 2 + mtl;
#pragma unroll
          for (int h = 0; h < 2; ++h) {
            f32x4 acc = {0.f, 0.f, 0.f, 0.f};
            acc = __builtin_amdgcn_mfma_f32_16x16x32_bf16(F[mt][0], Bae[h][0], acc, 0, 0, 0);
            acc = __builtin_amdgcn_mfma_f32_16x16x32_bf16(F[mt][1], Bae[h][1], acc, 0, 0, 0);
            put_tile(buf, l15, q, mtl, h,
                     pack2(acc[0] + bb[mt][0], acc[1] + bb[mt][1]),
                     pack2(acc[2] + bb[mt][2], acc[3] + bb[mt][3]));
          }
        }
        lds_fence();
#pragma unroll
        for (int h = 0; h < 2; ++h) Bin[h][4 + kt] = get_frag(buf, l15, q, h);
        lds_fence();
      }
    }
  }

  // ======== h1 = silu([nfi|nfj|ef] @ mg_w1 + b) -> Bh ========
  short8 Bh[2][4];
#pragma unroll
  for (int kt = 0; kt < 4; ++kt) {
    char* buf = my + (kt & 1) * TB;
#pragma unroll
    for (int mtl = 0; mtl < 2; ++mtl) {
      int mt = kt * 2 + mtl;
      short8 F[6];
#pragma unroll
      for (int ks = 0; ks < 6; ++ks)
        F[ks] = *(const short8*)(WF + (size_t)(24 + mt * 6 + ks) * 512 + lane * 8);
      f32x4 bb = *(const f32x4*)(mg_b1 + mt * 16 + 4 * q);
#pragma unroll
      for (int h = 0; h < 2; ++h) {
        f32x4 acc = {0.f, 0.f, 0.f, 0.f};
#pragma unroll
        for (int ks = 0; ks < 6; ++ks)
          acc = __builtin_amdgcn_mfma_f32_16x16x32_bf16(F[ks], Bin[h][ks], acc, 0, 0, 0);
        put_tile(buf, l15, q, mtl, h,
                 pack2(silu_f(acc[0] + bb[0]), silu_f(acc[1] + bb[1])),
                 pack2(silu_f(acc[2] + bb[2]), silu_f(acc[3] + bb[3])));
      }
    }
    lds_fence();
#pragma unroll
    for (int h = 0; h < 2; ++h) Bh[h][kt] = get_frag(buf, l15, q, h);
    lds_fence();
  }

  // ======== msg = h1 @ mg_w2 + b ========
  f32x4 msg[2][4];
#pragma unroll
  for (int mt = 0; mt < 4; ++mt) {
    short8 F[4];
#pragma unroll
    for (int ks = 0; ks < 4; ++ks)
      F[ks] = *(const short8*)(WF + (size_t)(72 + mt * 4 + ks) * 512 + lane * 8);
    f32x4 bb = *(const f32x4*)(mg_b2 + mt * 16 + 4 * q);
#pragma unroll
    for (int h = 0; h < 2; ++h) {
      f32x4 acc = {0.f, 0.f, 0.f, 0.f};
#pragma unroll
      for (int ks = 0; ks < 4; ++ks)
        acc = __builtin_amdgcn_mfma_f32_16x16x32_bf16(F[ks], Bh[h][ks], acc, 0, 0, 0);
      acc[0] += bb[0]; acc[1] += bb[1]; acc[2] += bb[2]; acc[3] += bb[3];
      msg[h][mt] = acc;
    }
  }

  // ======== coeff (reduce over quads) + v_agg scatter ========
  float part[2] = {0.f, 0.f};
#pragma unroll
  for (int mt = 0; mt < 4; ++mt) {
    f32x4 pw4 = *(const f32x4*)(pe_w + mt * 16 + 4 * q);
#pragma unroll
    for (int h = 0; h < 2; ++h)
      part[h] += msg[h][mt][0] * pw4[0] + msg[h][mt][1] * pw4[1] +
                 msg[h][mt][2] * pw4[2] + msg[h][mt][3] * pw4[3];
  }
  float peb = pe_b[0];
#pragma unroll
  for (int h = 0; h < 2; ++h) {
    part[h] += __shfl_xor(part[h], 16, 64);
    part[h] += __shfl_xor(part[h], 32, 64);
    if (q < 3) {
      float uc = (q == 0) ? uu0[h] : ((q == 1) ? uu1[h] : uu2[h]);
      atomicAdd(&v_agg[(size_t)rown[h] * 3 + q], uc * (part[h] + peb));
    }
  }

  // ======== s_agg scatter: transpose 8 edges at a time through LDS ========
#pragma unroll
  for (int h = 0; h < 2; ++h)
#pragma unroll
    for (int c = 0; c < 2; ++c) {
      if ((l15 >> 3) == c) {
#pragma unroll
        for (int mt = 0; mt < 4; ++mt)
          *(f32x4*)(my + (((l15 & 7) * 68 + mt * 16 + 4 * q) << 2)) = msg[h][mt];
      }
      lds_fence();
#pragma unroll
      for (int e = 0; e < 8; ++e) {
        int sr = __builtin_amdgcn_readlane(rown[h], c * 8 + e);
        float val = *(const float*)(my + ((e * 68 + lane) << 2));
        atomicAdd(&s_agg[(size_t)sr * D + lane], val);
      }
      lds_fence();
    }
}

// ---------------------------------------------------------------------------
// node_out: s_new = s + silu(s_agg)@up_w + up_b ; LayerNorm ; v normalize.
// ---------------------------------------------------------------------------
__global__ __launch_bounds__(256, 4) void node_out(
    const float* __restrict__ s, const float* __restrict__ v,
    const float* __restrict__ up_b,
    const float* __restrict__ ln_g, const float* __restrict__ ln_b,
    const float* __restrict__ s_agg, const float* __restrict__ v_agg,
    const unsigned short* __restrict__ WF, float* __restrict__ out) {
  __shared__ __align__(16) char sm[4 * 8704];
  int tid = threadIdx.x, w = tid >> 6, lane = tid & 63;
  int l15 = lane & 15, q = lane >> 4, fb = q * 8;
  char* my = sm + w * 8704;
  int nb = (blockIdx.x * 4 + w) * 32;
  if (nb >= NN) return;

  short8 Bg[2][2];
#pragma unroll
  for (int h = 0; h < 2; ++h)
#pragma unroll
    for (int kt = 0; kt < 2; ++kt) {
      int n = nb + h * 16 + l15; if (n >= NN) n = NN - 1;
      f32x4 g0 = *(const f32x4*)(s_agg + (size_t)n * D + kt * 32 + fb);
      f32x4 g1 = *(const f32x4*)(s_agg + (size_t)n * D + kt * 32 + fb + 4);
#pragma unroll
      for (int c2 = 0; c2 < 4; ++c2) { g0[c2] = silu_f(g0[c2]); g1[c2] = silu_f(g1[c2]); }
      Bg[h][kt] = pack_frag(g0, g1);
    }
  short8 F[4][2]; f32x4 bb[4];
#pragma unroll
  for (int mt = 0; mt < 4; ++mt) {
    F[mt][0] = *(const short8*)(WF + (size_t)(96 + mt * 2 + 0) * 512 + lane * 8);
    F[mt][1] = *(const short8*)(WF + (size_t)(96 + mt * 2 + 1) * 512 + lane * 8);
    bb[mt] = *(const f32x4*)(up_b + mt * 16 + 4 * q);
  }
  f32x4 sn[2][4];
#pragma unroll
  for (int h = 0; h < 2; ++h) {
    int n = nb + h * 16 + l15; if (n >= NN) n = NN - 1;
#pragma unroll
    for (int mt = 0; mt < 4; ++mt) {
      f32x4 acc = {0.f, 0.f, 0.f, 0.f};
      acc = __builtin_amdgcn_mfma_f32_16x16x32_bf16(F[mt][0], Bg[h][0], acc, 0, 0, 0);
      acc = __builtin_amdgcn_mfma_f32_16x16x32_bf16(F[mt][1], Bg[h][1], acc, 0, 0, 0);
      f32x4 sv = *(const f32x4*)(s + (size_t)n * D + mt * 16 + 4 * q);
      sn[h][mt][0] = acc[0] + bb[mt][0] + sv[0];
      sn[h][mt][1] = acc[1] + bb[mt][1] + sv[1];
      sn[h][mt][2] = acc[2] + bb[mt][2] + sv[2];
      sn[h][mt][3] = acc[3] + bb[mt][3] + sv[3];
    }
  }
#pragma unroll
  for (int h = 0; h < 2; ++h) {
    float m = 0.f;
#pragma unroll
    for (int mt = 0; mt < 4; ++mt)
      m += sn[h][mt][0] + sn[h][mt][1] + sn[h][mt][2] + sn[h][mt][3];
    m += __shfl_xor(m, 16, 64);
    m += __shfl_xor(m, 32, 64);
    float mu = m * (1.f / 64.f);
    float vv = 0.f;
#pragma unroll
    for (int mt = 0; mt < 4; ++mt)
#pragma unroll
      for (int r = 0; r < 4; ++r) {
        float d = sn[h][mt][r] - mu;
        vv += d * d;
      }
    vv += __shfl_xor(vv, 16, 64);
    vv += __shfl_xor(vv, 32, 64);
    float inv = 1.f / sqrtf(vv * (1.f / 64.f) + 1e-5f);
#pragma unroll
    for (int mt = 0; mt < 4; ++mt) {
      f32x4 lg = *(const f32x4*)(ln_g + mt * 16 + 4 * q);
      f32x4 lb = *(const f32x4*)(ln_b + mt * 16 + 4 * q);
      f32x4 ov;
#pragma unroll
      for (int r = 0; r < 4; ++r) ov[r] = (sn[h][mt][r] - mu) * inv * lg[r] + lb[r];
      *(f32x4*)(my + (((h * 16 + l15) * 68 + mt * 16 + 4 * q) << 2)) = ov;
    }
  }
  lds_fence();
#pragma unroll
  for (int h = 0; h < 2; ++h)
#pragma unroll
    for (int e = 0; e < 16; ++e) {
      int n = nb + h * 16 + e;
      if (n < NN) {
        float val = *(const float*)(my + (((h * 16 + e) * 68 + lane) << 2));
        out[(size_t)n * D + lane] = val;
      }
    }
#pragma unroll
  for (int h = 0; h < 2; ++h) {
    int n = nb + h * 16 + l15;
    if (q < 3 && n < NN) {
      float v0 = v[n * 3 + 0] + v_agg[(size_t)n * 3 + 0];
      float v1 = v[n * 3 + 1] + v_agg[(size_t)n * 3 + 1];
      float v2 = v[n * 3 + 2] + v_agg[(size_t)n * 3 + 2];
      float nrm = sqrtf(v0 * v0 + v1 * v1 + v2 * v2);
      float denom = fmaxf(nrm, 1e-6f);
      float val = (q == 0) ? v0 : ((q == 1) ? v1 : v2);
      out[(size_t)NN * D + (size_t)n * 3 + q] = val / denom;
    }
  }
}

// ---------------------------------------------------------------------------
extern "C" void kernel_launch(void* const* d_in, const int* in_sizes, int n_in,
                              void* d_out, int out_size, void* d_ws, size_t ws_size,
                              hipStream_t stream) {
  const float* s         = (const float*)d_in[0];
  const float* v         = (const float*)d_in[1];
  const int*   ei        = (const int*)d_in[2];
  const float* edge_attr = (const float*)d_in[3];
  const float* evu       = (const float*)d_in[4];
  const float* ng_w1     = (const float*)d_in[5];
  const float* ng_b1     = (const float*)d_in[6];
  const float* ng_w2     = (const float*)d_in[7];
  const float* ng_b2     = (const float*)d_in[8];
  const float* eg_w1     = (const float*)d_in[9];
  const float* eg_b1     = (const float*)d_in[10];
  const float* eg_w2     = (const float*)d_in[11];
  const float* eg_b2     = (const float*)d_in[12];
  const float* mg_w1     = (const float*)d_in[13];
  const float* mg_b1     = (const float*)d_in[14];
  const float* mg_w2     = (const float*)d_in[15];
  const float* mg_b2     = (const float*)d_in[16];
  const float* pe_w      = (const float*)d_in[17];
  const float* pe_b      = (const float*)d_in[18];
  const float* up_w      = (const float*)d_in[19];
  const float* up_b      = (const float*)d_in[20];
  const float* ln_g      = (const float*)d_in[21];
  const float* ln_b      = (const float*)d_in[22];
  (void)in_sizes; (void)n_in; (void)out_size; (void)ws_size;

  float* out   = (float*)d_out;
  float* s_agg = (float*)d_ws;                            // NN*64 floats
  float* v_agg = s_agg + (size_t)NN * D;                  // NN*3 floats
  unsigned short* WF = (unsigned short*)(v_agg + (size_t)NN * 3);  // 104 frags * 512 bf16
  float* h_ng  = out;  // d_out[0..NN*64) as scratch; node_out overwrites later

  hipMemsetAsync(d_ws, 0, (size_t)(NN * D + NN * 3) * sizeof(float), stream);

  prep_all<<<26, 256, 0, stream>>>(ng_w2, eg_w1, eg_w2, mg_w1, mg_w2, ng_w1, up_w, WF);

  int node_blocks = (NN + 127) / 128;  // 32 nodes/wave * 4 waves
  node_pre<<<node_blocks, 256, 0, stream>>>(s, ng_b1, WF, h_ng);

  edge_mfma<<<NE / 128, 256, 0, stream>>>(
      v, ei, edge_attr, evu,
      ng_w1, ng_b2, eg_w1, eg_b1, eg_b2,
      mg_b1, mg_b2, pe_w, pe_b, h_ng, WF, s_agg, v_agg);

  node_out<<<node_blocks, 256, 0, stream>>>(
      s, v, up_b, ln_g, ln_b, s_agg, v_agg, WF, out);
}